// Round 10
// baseline (500.862 us; speedup 1.0000x reference)
//
#include <hip/hip_runtime.h>

// ---------------------------------------------------------------------------
// DecoderBlock: x = LN1(x + SelfAttn(x));  x = LN2(x + CrossAttn(x, mem));
//               x = LN3(x + W2·relu(W1·x + b1) + b2)
// B=2, N=2048, M=1024, D=1024, H=16, Dh=64, FF=4096.
// R10: (1) self-QKV + cross-KV merged into one 128x128 dual dispatch (1024
//      blocks = 4/CU; cross-KV only depends on memb). (2) O-proj split-K 2->4
//      (2048 blocks = 8/CU; these are the most latency-bound GEMMs).
//      (3) ws re-laid out (kvb no longer aliases qkv). Rest = R9.
// ---------------------------------------------------------------------------

typedef __attribute__((ext_vector_type(8))) short bf16x8;   // 8 bf16 (4 VGPRs)
typedef __attribute__((ext_vector_type(4))) float f32x4;

__device__ __forceinline__ unsigned short f2bf(float f) {
    union { float f; unsigned int u; } v; v.f = f;
    unsigned int r = v.u + 0x7fffu + ((v.u >> 16) & 1u);   // RNE
    return (unsigned short)(r >> 16);
}
__device__ __forceinline__ float bf2f(unsigned short u) {
    union { unsigned int u; float f; } v; v.u = (unsigned int)u << 16;
    return v.f;
}
__device__ __forceinline__ unsigned int bftrunc(float f) {
    union { float f; unsigned int u; } v; v.f = f;
    return v.u >> 16;                                      // truncation (P only)
}

// --------------------------- fused fp32 -> bf16 conversion -----------------
struct ConvArgs {
    const float* src[12];
    unsigned short* dst[12];
    int blk_ofs[13];
    int n4[12];
};
__global__ __launch_bounds__(256) void conv_multi(ConvArgs a)
{
    int bid = blockIdx.x;
    int s = 0;
#pragma unroll
    for (int t = 0; t < 12; ++t) if (bid >= a.blk_ofs[t + 1]) s = t + 1;
    int i = (bid - a.blk_ofs[s]) * 256 + threadIdx.x;
    if (i >= a.n4[s]) return;
    float4 v = ((const float4*)a.src[s])[i];
    ushort4 o;
    o.x = f2bf(v.x); o.y = f2bf(v.y); o.z = f2bf(v.z); o.w = f2bf(v.w);
    ((ushort4*)a.dst[s])[i] = o;
}

// --------------------------- bias concat (fp32) ----------------------------
__global__ __launch_bounds__(256) void concat_bias(
    const float* __restrict__ bq, const float* __restrict__ bk,
    const float* __restrict__ bv, const float* __restrict__ ck,
    const float* __restrict__ cv, float* __restrict__ bqkv,
    float* __restrict__ bkvc)
{
    int i = blockIdx.x * 256 + threadIdx.x;       // 0..5119
    if (i < 1024)       bqkv[i] = bq[i];
    else if (i < 2048)  bqkv[i] = bk[i - 1024];
    else if (i < 3072)  bqkv[i] = bv[i - 2048];
    else if (i < 4096)  bkvc[i - 3072] = ck[i - 3072];
    else if (i < 5120)  bkvc[i - 3072] = cv[i - 4096];
}

// --------------------------- bf16 GEMM core --------------------------------
// TM x TN tile, BK=64, 256 threads, global_load_lds width-16 staging,
// XOR-swizzled LDS (conflict-free, verified R8: SQ_LDS_BANK_CONFLICT = 0).
// All outputs bf16. EPI: 0 = plain, 1 = relu. SK>1: bf16 partial slices at
// out + z*slice_stride, bias added only in slice 0.
template<int TM, int TN, int EPI, int SK>
__device__ __forceinline__ void gemm_body(
    unsigned short (*As)[64], unsigned short (*Bs)[64],
    const unsigned short* __restrict__ A, const unsigned short* __restrict__ W,
    const float* __restrict__ bias, unsigned short* __restrict__ out,
    int K, int Ncols, long slice_stride, int bid, int gx, int zslice)
{
    constexpr int AI = TM / 32;
    constexpr int BJ = TN / 32;

    const int tid  = threadIdx.x;
    const int lane = tid & 63;
    const int wave = tid >> 6;
    const int qd   = lane >> 4;
    const int l15  = lane & 15;
    const int wm   = (wave >> 1) * (TM / 2);
    const int wn   = (wave & 1) * (TN / 2);

    const int gpg = 8 * gx;                       // GROUP_M=8 swizzle
    const long m0 = (long)((bid / gpg) * 8 + (bid & 7)) * TM;
    const long n0 = (long)((bid % gpg) >> 3) * TN;

    f32x4 acc[AI][BJ] = {};

    const int srow = lane >> 3;
    const int scol = (((lane & 7) ^ srow)) * 8;   // XOR-swizzled group
    const unsigned short* Ag = A + (m0 + wave * (8 * AI) + srow) * (long)K + scol;
    const unsigned short* Wg = W + (n0 + wave * (8 * BJ) + srow) * (long)K + scol;

    const int ksl   = K / SK;
    const int kbase = (SK > 1) ? zslice * ksl : 0;

    for (int k0 = kbase; k0 < kbase + ksl; k0 += 64) {
#pragma unroll
        for (int c = 0; c < AI; ++c)
            __builtin_amdgcn_global_load_lds(
                (const __attribute__((address_space(1))) unsigned int*)(Ag + (long)c * 8 * K + k0),
                (__attribute__((address_space(3))) unsigned int*)((char*)&As[0][0] + (wave * AI + c) * 1024),
                16, 0, 0);
#pragma unroll
        for (int c = 0; c < BJ; ++c)
            __builtin_amdgcn_global_load_lds(
                (const __attribute__((address_space(1))) unsigned int*)(Wg + (long)c * 8 * K + k0),
                (__attribute__((address_space(3))) unsigned int*)((char*)&Bs[0][0] + (wave * BJ + c) * 1024),
                16, 0, 0);
        __syncthreads();
#pragma unroll
        for (int kk = 0; kk < 64; kk += 32) {
            const int pg = ((((kk >> 3) + qd)) ^ (l15 & 7)) * 8;  // de-swizzle
            bf16x8 af[AI], bw[BJ];
#pragma unroll
            for (int i = 0; i < AI; ++i)
                af[i] = *(const bf16x8*)&As[wm + i * 16 + l15][pg];
#pragma unroll
            for (int j = 0; j < BJ; ++j)
                bw[j] = *(const bf16x8*)&Bs[wn + j * 16 + l15][pg];
#pragma unroll
            for (int i = 0; i < AI; ++i)
#pragma unroll
                for (int j = 0; j < BJ; ++j)
                    acc[i][j] = __builtin_amdgcn_mfma_f32_16x16x32_bf16(
                        af[i], bw[j], acc[i][j], 0, 0, 0);
        }
        __syncthreads();
    }

    // epilogue. C/D layout: col = lane&15, row = quad*4 + reg  [m89-verified]
    unsigned short* op = out + ((SK > 1) ? (long)zslice * slice_stride : 0);
#pragma unroll
    for (int j = 0; j < BJ; ++j) {
        long col = n0 + wn + j * 16 + l15;
        float bv = (SK == 1 || zslice == 0) ? bias[col] : 0.f;
#pragma unroll
        for (int i = 0; i < AI; ++i) {
#pragma unroll
            for (int r = 0; r < 4; ++r) {
                long row = m0 + wm + i * 16 + qd * 4 + r;
                float v = acc[i][j][r] + bv;
                if (EPI == 1) v = (v > 0.f) ? v : 0.f;
                op[row * Ncols + col] = f2bf(v);
            }
        }
    }
}

template<int TM, int TN, int EPI, int SK>
__global__ __launch_bounds__(256) void gemm_bt(
    const unsigned short* __restrict__ A, const unsigned short* __restrict__ W,
    const float* __restrict__ bias, unsigned short* __restrict__ out,
    int K, int Ncols, long slice_stride)
{
    __shared__ unsigned short As[TM][64];
    __shared__ unsigned short Bs[TN][64];
    const int bid = blockIdx.y * gridDim.x + blockIdx.x;
    gemm_body<TM, TN, EPI, SK>(As, Bs, A, W, bias, out, K, Ncols, slice_stride,
                               bid, gridDim.x, (int)blockIdx.z);
}

// Two independent GEMMs (same tile shape) in one dispatch: blocks [0,nb0) run
// problem 0, the rest run problem 1. Used for selfQKV + crossKV.
template<int TM, int TN>
__global__ __launch_bounds__(256) void gemm_bt_dual(
    const unsigned short* A0, const unsigned short* W0, const float* b0,
    unsigned short* o0, int K0, int N0, int gx0, int nb0,
    const unsigned short* A1, const unsigned short* W1, const float* b1,
    unsigned short* o1, int K1, int N1, int gx1)
{
    __shared__ unsigned short As[TM][64];
    __shared__ unsigned short Bs[TN][64];
    const int bid = blockIdx.x;
    if (bid < nb0)
        gemm_body<TM, TN, 0, 1>(As, Bs, A0, W0, b0, o0, K0, N0, 0, bid, gx0, 0);
    else
        gemm_body<TM, TN, 0, 1>(As, Bs, A1, W1, b1, o1, K1, N1, 0, bid - nb0, gx1, 0);
}

// --------------------------- flash attention (MFMA, 4-wave, 64q) -----------
// 64 queries/block, 1 q-tile/wave, 4 blocks/CU, fixed-reference softmax
// (M=0 exact: shift-invariance + O(1) scores), permuted key order
// key' = (k&15)*4 + (k>>4) in P and V, 2-stage K/V prefetch.
__global__ __launch_bounds__(256) void attn_kernel(
    const unsigned short* __restrict__ Qb, int q_stride,
    const unsigned short* __restrict__ KVb, int kv_stride, int koff, int voff,
    unsigned short* __restrict__ O,
    int Nq, int Mk, int causal)
{
    __shared__ unsigned short Ks[64][72];
    __shared__ unsigned short Vs[64][72];
    __shared__ unsigned short Ps[4][16][72];

    const int tid  = threadIdx.x;
    const int lane = tid & 63;
    const int wave = tid >> 6;
    const int qd   = lane >> 4;
    const int l15  = lane & 15;
    const int h    = blockIdx.y;
    const int b    = blockIdx.z;
    int jq = blockIdx.x;
    if (causal && (b & 1)) jq = gridDim.x - 1 - jq;
    const int q0 = jq * 64;
    const int tb = q0 + wave * 16;

    bf16x8 aq0, aq1;
    {
        const unsigned short* qp =
            Qb + (long)(b * Nq + tb + l15) * q_stride + h * 64 + qd * 8;
        aq0 = *(const bf16x8*)qp;
        aq1 = *(const bf16x8*)(qp + 32);
    }

    float lpart[4] = {};
    f32x4 oacc[4] = {};

    const int krow = tid >> 3;
    const int kcol = (tid & 7) * 8;
    const int vj   = tid & 31;
    const int va_k = (vj & 15) + ((vj & 16) << 1);
    const int vfg  = (tid >> 5) * 8;
    const int vpc  = (va_k & 15) * 4 + (va_k >> 4);

    const unsigned short* Kg = KVb + (long)b * Mk * kv_stride + koff + h * 64;
    const unsigned short* Vg = KVb + (long)b * Mk * kv_stride + voff + h * 64;

    bf16x8 kr0, kr1, vra, vrb;
    auto prefetch = [&](int k0) {
        kr0 = *(const bf16x8*)(Kg + (long)(k0 + krow) * kv_stride + kcol);
        kr1 = *(const bf16x8*)(Kg + (long)(k0 + krow + 32) * kv_stride + kcol);
        const unsigned short* v0 = Vg + (long)(k0 + va_k) * kv_stride + vfg;
        vra = *(const bf16x8*)v0;
        vrb = *(const bf16x8*)(v0 + 16 * kv_stride);
    };

    const int nk = causal ? (q0 + 64) : Mk;
    prefetch(0);
    const float SCL = 0.125f * 1.44269504f;

    for (int k0 = 0; k0 < nk; k0 += 64) {
        __syncthreads();
        *(bf16x8*)&Ks[krow][kcol]      = kr0;
        *(bf16x8*)&Ks[krow + 32][kcol] = kr1;
#pragma unroll
        for (int jf = 0; jf < 8; ++jf) {
            unsigned int d = (unsigned short)vra[jf] |
                             ((unsigned int)(unsigned short)vrb[jf] << 16);
            *(unsigned int*)&Vs[vfg + jf][vpc] = d;
        }
        if (k0 + 64 < nk) prefetch(k0 + 64);
        __syncthreads();

        if (!causal || (k0 <= tb + 15)) {
            bf16x8 bk[4][2];
#pragma unroll
            for (int kt = 0; kt < 4; ++kt)
#pragma unroll
                for (int c = 0; c < 2; ++c)
                    bk[kt][c] = *(const bf16x8*)&Ks[kt * 16 + l15][c * 32 + qd * 8];
            f32x4 s[4];
#pragma unroll
            for (int kt = 0; kt < 4; ++kt) {
                f32x4 z = {};
                z = __builtin_amdgcn_mfma_f32_16x16x32_bf16(aq0, bk[kt][0], z, 0, 0, 0);
                z = __builtin_amdgcn_mfma_f32_16x16x32_bf16(aq1, bk[kt][1], z, 0, 0, 0);
                s[kt] = z;
            }
            const bool needmask = causal && (k0 + 63 > tb);
#pragma unroll
            for (int r = 0; r < 4; ++r) {
                const int qg = tb + qd * 4 + r;
                float e[4];
#pragma unroll
                for (int kt = 0; kt < 4; ++kt) {
                    float ev = __builtin_amdgcn_exp2f(s[kt][r] * SCL);
                    if (needmask && (k0 + kt * 16 + l15 > qg)) ev = 0.f;
                    e[kt] = ev;
                }
                lpart[r] += (e[0] + e[1]) + (e[2] + e[3]);
                unsigned int lo = bftrunc(e[0]) | (bftrunc(e[1]) << 16);
                unsigned int hi = bftrunc(e[2]) | (bftrunc(e[3]) << 16);
                uint2 pk; pk.x = lo; pk.y = hi;
                *(uint2*)&Ps[wave][qd * 4 + r][l15 * 4] = pk;
            }
            bf16x8 bv[4][2];
#pragma unroll
            for (int dt = 0; dt < 4; ++dt)
#pragma unroll
                for (int c = 0; c < 2; ++c)
                    bv[dt][c] = *(const bf16x8*)&Vs[dt * 16 + l15][c * 32 + qd * 8];
            bf16x8 ap0 = *(const bf16x8*)&Ps[wave][l15][qd * 8];
            bf16x8 ap1 = *(const bf16x8*)&Ps[wave][l15][32 + qd * 8];
#pragma unroll
            for (int dt = 0; dt < 4; ++dt) {
                oacc[dt] = __builtin_amdgcn_mfma_f32_16x16x32_bf16(
                    ap0, bv[dt][0], oacc[dt], 0, 0, 0);
                oacc[dt] = __builtin_amdgcn_mfma_f32_16x16x32_bf16(
                    ap1, bv[dt][1], oacc[dt], 0, 0, 0);
            }
        }
    }

#pragma unroll
    for (int r = 0; r < 4; ++r) {
        float l = lpart[r];
        l += __shfl_xor(l, 1);
        l += __shfl_xor(l, 2);
        l += __shfl_xor(l, 4);
        l += __shfl_xor(l, 8);
        float inv = 1.f / l;
        long row = (long)(b * Nq + tb + qd * 4 + r);
#pragma unroll
        for (int dt = 0; dt < 4; ++dt)
            O[row * 1024 + h * 64 + dt * 16 + l15] = f2bf(oacc[dt][r] * inv);
    }
}

// --------------------------- residual + LayerNorm --------------------------
// res: fp32 (RESBF=0) or bf16 (RESBF=1). ND bf16 delta slices.
template<int ND, int RESBF>
__global__ __launch_bounds__(256) void ln_res_kernel(
    const void* __restrict__ res, const unsigned short* __restrict__ delta,
    long dstride, const float* __restrict__ g, const float* __restrict__ beta,
    float* __restrict__ yout, unsigned short* __restrict__ ybf)
{
    __shared__ float red[8];
    const int row = blockIdx.x;
    const int tid = threadIdx.x;
    const long base = (long)row * 1024 + tid * 4;
    float v0, v1, v2, v3;
    if (RESBF) {
        ushort4 a = *(const ushort4*)((const unsigned short*)res + base);
        v0 = bf2f(a.x); v1 = bf2f(a.y); v2 = bf2f(a.z); v3 = bf2f(a.w);
    } else {
        float4 a = *(const float4*)((const float*)res + base);
        v0 = a.x; v1 = a.y; v2 = a.z; v3 = a.w;
    }
#pragma unroll
    for (int t = 0; t < ND; ++t) {
        ushort4 d = *(const ushort4*)(delta + t * dstride + base);
        v0 += bf2f(d.x); v1 += bf2f(d.y); v2 += bf2f(d.z); v3 += bf2f(d.w);
    }
    float s  = v0 + v1 + v2 + v3;
    float ss = v0 * v0 + v1 * v1 + v2 * v2 + v3 * v3;
#pragma unroll
    for (int off = 1; off < 64; off <<= 1) {
        s  += __shfl_xor(s, off);
        ss += __shfl_xor(ss, off);
    }
    const int wave = tid >> 6;
    if ((tid & 63) == 0) { red[wave] = s; red[4 + wave] = ss; }
    __syncthreads();
    float st  = red[0] + red[1] + red[2] + red[3];
    float sst = red[4] + red[5] + red[6] + red[7];
    float mean = st * (1.f / 1024.f);
    float var  = sst * (1.f / 1024.f) - mean * mean;
    float inv  = rsqrtf(var + 1e-5f);
    const int c = tid * 4;
    float y0 = (v0 - mean) * inv * g[c + 0] + beta[c + 0];
    float y1 = (v1 - mean) * inv * g[c + 1] + beta[c + 1];
    float y2 = (v2 - mean) * inv * g[c + 2] + beta[c + 2];
    float y3 = (v3 - mean) * inv * g[c + 3] + beta[c + 3];
    if (yout) *(float4*)(yout + base) = make_float4(y0, y1, y2, y3);
    if (ybf) {
        ushort4 o;
        o.x = f2bf(y0); o.y = f2bf(y1); o.z = f2bf(y2); o.w = f2bf(y3);
        *(ushort4*)(ybf + base) = o;
    }
}

// --------------------------- launch ----------------------------------------
extern "C" void kernel_launch(void* const* d_in, const int* in_sizes, int n_in,
                              void* d_out, int out_size, void* d_ws, size_t ws_size,
                              hipStream_t stream)
{
    const int B = 2, N = 2048, M = 1024, D = 1024, FF = 4096;
    const int TN = B * N;   // 4096
    const int TM = B * M;   // 2048
    const size_t MB = 1024 * 1024;

    const float* x     = (const float*)d_in[0];
    const float* mem   = (const float*)d_in[1];
    const float* sa_wq = (const float*)d_in[3];  const float* sa_bq = (const float*)d_in[4];
    const float* sa_wk = (const float*)d_in[5];  const float* sa_bk = (const float*)d_in[6];
    const float* sa_wv = (const float*)d_in[7];  const float* sa_bv = (const float*)d_in[8];
    const float* sa_wo = (const float*)d_in[9];  const float* sa_bo = (const float*)d_in[10];
    const float* ca_wq = (const float*)d_in[11]; const float* ca_bq = (const float*)d_in[12];
    const float* ca_wk = (const float*)d_in[13]; const float* ca_bk = (const float*)d_in[14];
    const float* ca_wv = (const float*)d_in[15]; const float* ca_bv = (const float*)d_in[16];
    const float* ca_wo = (const float*)d_in[17]; const float* ca_bo = (const float*)d_in[18];
    const float* ff_w1 = (const float*)d_in[19]; const float* ff_b1 = (const float*)d_in[20];
    const float* ff_w2 = (const float*)d_in[21]; const float* ff_b2 = (const float*)d_in[22];
    const float* ln1_g = (const float*)d_in[23]; const float* ln1_b = (const float*)d_in[24];
    const float* ln2_g = (const float*)d_in[25]; const float* ln2_b = (const float*)d_in[26];
    const float* ln3_g = (const float*)d_in[27]; const float* ln3_b = (const float*)d_in[28];

    char* w = (char*)d_ws;
    size_t off = 0;
    auto alloc = [&](size_t bytes) -> char* {
        char* p = w + off; off += (bytes + 255) & ~(size_t)255; return p;
    };

    unsigned short* xb   = (unsigned short*)alloc((size_t)TN * D * 2);   // 8 MB
    unsigned short* memb = (unsigned short*)alloc((size_t)TM * D * 2);   // 4 MB
    unsigned short* wqkv = (unsigned short*)alloc((size_t)3 * D * D * 2);// 6 MB
    unsigned short* wos  = (unsigned short*)alloc((size_t)D * D * 2);
    unsigned short* wqc  = (unsigned short*)alloc((size_t)D * D * 2);
    unsigned short* wkvc = (unsigned short*)alloc((size_t)2 * D * D * 2);// 4 MB
    unsigned short* woc  = (unsigned short*)alloc((size_t)D * D * 2);
    unsigned short* w1b  = (unsigned short*)alloc((size_t)FF * D * 2);   // 8 MB
    unsigned short* w2b  = (unsigned short*)alloc((size_t)D * FF * 2);   // 8 MB
    // big overlapped region (80 MB):
    //   phase1: qkv [0,24)  ab [24,32)  kvb [32,40)  (kvb produced early now)
    //   phase2: qb [40,48)  kvb [32,40) ab [24,32)
    //   phase3: hb [0,32)
    //   O-proj/FFN2 partials: tmpbf [48,80) (4 x 8 MB bf16 slices)
    char* big = alloc((size_t)80 * MB);
    unsigned short* qkv   = (unsigned short*)big;
    unsigned short* ab    = (unsigned short*)(big + 24 * MB);
    unsigned short* kvb   = (unsigned short*)(big + 32 * MB);
    unsigned short* qb    = (unsigned short*)(big + 40 * MB);
    unsigned short* hb    = (unsigned short*)big;
    unsigned short* tmpbf = (unsigned short*)(big + 48 * MB);
    const long      TSL   = (long)TN * D;        // slice stride (elements)
    float* bqkv = (float*)alloc((size_t)3 * D * 4);
    float* bkvc = (float*)alloc((size_t)2 * D * 4);

    // ---- fused fp32->bf16 conversions (one launch) ----
    ConvArgs ca;
    const float* srcs[12] = {x, mem, sa_wq, sa_wk, sa_wv, sa_wo,
                             ca_wq, ca_wk, ca_wv, ca_wo, ff_w1, ff_w2};
    unsigned short* dsts[12] = {xb, memb, wqkv, wqkv + (size_t)D * D,
                                wqkv + (size_t)2 * D * D, wos, wqc, wkvc,
                                wkvc + (size_t)D * D, woc, w1b, w2b};
    long ns[12] = {(long)TN * D, (long)TM * D, (long)D * D, (long)D * D,
                   (long)D * D, (long)D * D, (long)D * D, (long)D * D,
                   (long)D * D, (long)D * D, (long)FF * D, (long)D * FF};
    int total_blk = 0;
    for (int i = 0; i < 12; ++i) {
        ca.src[i] = srcs[i]; ca.dst[i] = dsts[i];
        ca.n4[i] = (int)(ns[i] / 4);
        ca.blk_ofs[i] = total_blk;
        total_blk += (ca.n4[i] + 255) / 256;
    }
    ca.blk_ofs[12] = total_blk;
    conv_multi<<<dim3(total_blk), dim3(256), 0, stream>>>(ca);
    concat_bias<<<dim3(20), dim3(256), 0, stream>>>(
        sa_bq, sa_bk, sa_bv, ca_bk, ca_bv, bqkv, bkvc);

    dim3 blk(256);

    // ---- projections: self QKV (768 blocks) + cross KV (256 blocks) -------
    gemm_bt_dual<128, 128><<<dim3(1024), blk, 0, stream>>>(
        xb,   wqkv, bqkv, qkv, D, 3 * D, 3 * D / 128, 768,
        memb, wkvc, bkvc, kvb, D, 2 * D, 2 * D / 128);

    // ---- self-attention ----
    attn_kernel<<<dim3(N / 64, 16, B), blk, 0, stream>>>(
        qkv, 3 * D, qkv, 3 * D, D, 2 * D, ab, N, N, 1);
    gemm_bt<128, 64, 0, 4><<<dim3(D / 64, TN / 128, 4), blk, 0, stream>>>(
        ab, wos, sa_bo, tmpbf, D, D, TSL);
    ln_res_kernel<4, 0><<<dim3(TN), blk, 0, stream>>>(
        x, tmpbf, TSL, ln1_g, ln1_b, nullptr, xb);

    // ---- cross-attention ----
    gemm_bt<128, 64, 0, 1><<<dim3(D / 64, TN / 128), blk, 0, stream>>>(
        xb, wqc, ca_bq, qb, D, D, 0);
    attn_kernel<<<dim3(N / 64, 16, B), blk, 0, stream>>>(
        qb, D, kvb, 2 * D, 0, D, ab, N, M, 0);
    gemm_bt<128, 64, 0, 4><<<dim3(D / 64, TN / 128, 4), blk, 0, stream>>>(
        ab, woc, ca_bo, tmpbf, D, D, TSL);
    ln_res_kernel<4, 1><<<dim3(TN), blk, 0, stream>>>(
        xb, tmpbf, TSL, ln2_g, ln2_b, nullptr, xb);

    // ---- FFN ----
    gemm_bt<128, 128, 1, 1><<<dim3(FF / 128, TN / 128), blk, 0, stream>>>(
        xb, w1b, ff_b1, hb, D, FF, 0);
    gemm_bt<128, 64, 0, 4><<<dim3(D / 64, TN / 128, 4), blk, 0, stream>>>(
        hb, w2b, ff_b2, tmpbf, FF, D, TSL);
    ln_res_kernel<4, 1><<<dim3(TN), blk, 0, stream>>>(
        xb, tmpbf, TSL, ln3_g, ln3_b, (float*)d_out, nullptr);
}

// Round 11
// 487.357 us; speedup vs baseline: 1.0277x; 1.0277x over previous
//
#include <hip/hip_runtime.h>

// ---------------------------------------------------------------------------
// DecoderBlock: x = LN1(x + SelfAttn(x));  x = LN2(x + CrossAttn(x, mem));
//               x = LN3(x + W2·relu(W1·x + b1) + b2)
// B=2, N=2048, M=1024, D=1024, H=16, Dh=64, FF=4096.
// R11 = R9 (489us, best) + two deltas:
//   (1) QKV gemm 128x128 -> 128x64 (1536 blocks ~5-6/CU, was 768 = 3/CU).
//   (2) concat_bias folded into conv_multi (one fewer graph node).
// R10's O-proj SK4 reverted (partial-write traffic beat the latency gain).
// ---------------------------------------------------------------------------

typedef __attribute__((ext_vector_type(8))) short bf16x8;   // 8 bf16 (4 VGPRs)
typedef __attribute__((ext_vector_type(4))) float f32x4;

__device__ __forceinline__ unsigned short f2bf(float f) {
    union { float f; unsigned int u; } v; v.f = f;
    unsigned int r = v.u + 0x7fffu + ((v.u >> 16) & 1u);   // RNE
    return (unsigned short)(r >> 16);
}
__device__ __forceinline__ float bf2f(unsigned short u) {
    union { unsigned int u; float f; } v; v.u = (unsigned int)u << 16;
    return v.f;
}
__device__ __forceinline__ unsigned int bftrunc(float f) {
    union { float f; unsigned int u; } v; v.f = f;
    return v.u >> 16;                                      // truncation (P only)
}

// ------------------- fused fp32->bf16 conversion + bias concat -------------
struct ConvArgs {
    const float* src[12];
    unsigned short* dst[12];
    int blk_ofs[13];
    int n4[12];
    // bias concat tail (fp32 copies), blocks [blk_ofs[12], blk_ofs[12]+20)
    const float* bq; const float* bk; const float* bv;
    const float* ck; const float* cv;
    float* bqkv; float* bkvc;
};
__global__ __launch_bounds__(256) void conv_multi(ConvArgs a)
{
    int bid = blockIdx.x;
    if (bid >= a.blk_ofs[12]) {                  // bias-concat tail
        int i = (bid - a.blk_ofs[12]) * 256 + threadIdx.x;   // 0..5119
        if (i < 1024)       a.bqkv[i] = a.bq[i];
        else if (i < 2048)  a.bqkv[i] = a.bk[i - 1024];
        else if (i < 3072)  a.bqkv[i] = a.bv[i - 2048];
        else if (i < 4096)  a.bkvc[i - 3072] = a.ck[i - 3072];
        else if (i < 5120)  a.bkvc[i - 3072] = a.cv[i - 4096];
        return;
    }
    int s = 0;
#pragma unroll
    for (int t = 0; t < 12; ++t) if (bid >= a.blk_ofs[t + 1]) s = t + 1;
    int i = (bid - a.blk_ofs[s]) * 256 + threadIdx.x;
    if (i >= a.n4[s]) return;
    float4 v = ((const float4*)a.src[s])[i];
    ushort4 o;
    o.x = f2bf(v.x); o.y = f2bf(v.y); o.z = f2bf(v.z); o.w = f2bf(v.w);
    ((ushort4*)a.dst[s])[i] = o;
}

// --------------------------- bf16 GEMM core --------------------------------
// TM x TN tile, BK=64, 256 threads, global_load_lds width-16 staging,
// XOR-swizzled LDS (conflict-free; verified R8: SQ_LDS_BANK_CONFLICT = 0).
// All outputs bf16. EPI: 0 = plain, 1 = relu. SK>1: bf16 partial slices at
// out + z*slice_stride, bias added only in slice 0.
template<int TM, int TN, int EPI, int SK>
__device__ __forceinline__ void gemm_body(
    unsigned short (*As)[64], unsigned short (*Bs)[64],
    const unsigned short* __restrict__ A, const unsigned short* __restrict__ W,
    const float* __restrict__ bias, unsigned short* __restrict__ out,
    int K, int Ncols, long slice_stride, int bid, int gx, int zslice)
{
    constexpr int AI = TM / 32;
    constexpr int BJ = TN / 32;

    const int tid  = threadIdx.x;
    const int lane = tid & 63;
    const int wave = tid >> 6;
    const int qd   = lane >> 4;
    const int l15  = lane & 15;
    const int wm   = (wave >> 1) * (TM / 2);
    const int wn   = (wave & 1) * (TN / 2);

    const int gpg = 8 * gx;                       // GROUP_M=8 swizzle
    const long m0 = (long)((bid / gpg) * 8 + (bid & 7)) * TM;
    const long n0 = (long)((bid % gpg) >> 3) * TN;

    f32x4 acc[AI][BJ] = {};

    const int srow = lane >> 3;
    const int scol = (((lane & 7) ^ srow)) * 8;   // XOR-swizzled group
    const unsigned short* Ag = A + (m0 + wave * (8 * AI) + srow) * (long)K + scol;
    const unsigned short* Wg = W + (n0 + wave * (8 * BJ) + srow) * (long)K + scol;

    const int ksl   = K / SK;
    const int kbase = (SK > 1) ? zslice * ksl : 0;

    for (int k0 = kbase; k0 < kbase + ksl; k0 += 64) {
#pragma unroll
        for (int c = 0; c < AI; ++c)
            __builtin_amdgcn_global_load_lds(
                (const __attribute__((address_space(1))) unsigned int*)(Ag + (long)c * 8 * K + k0),
                (__attribute__((address_space(3))) unsigned int*)((char*)&As[0][0] + (wave * AI + c) * 1024),
                16, 0, 0);
#pragma unroll
        for (int c = 0; c < BJ; ++c)
            __builtin_amdgcn_global_load_lds(
                (const __attribute__((address_space(1))) unsigned int*)(Wg + (long)c * 8 * K + k0),
                (__attribute__((address_space(3))) unsigned int*)((char*)&Bs[0][0] + (wave * BJ + c) * 1024),
                16, 0, 0);
        __syncthreads();
#pragma unroll
        for (int kk = 0; kk < 64; kk += 32) {
            const int pg = ((((kk >> 3) + qd)) ^ (l15 & 7)) * 8;  // de-swizzle
            bf16x8 af[AI], bw[BJ];
#pragma unroll
            for (int i = 0; i < AI; ++i)
                af[i] = *(const bf16x8*)&As[wm + i * 16 + l15][pg];
#pragma unroll
            for (int j = 0; j < BJ; ++j)
                bw[j] = *(const bf16x8*)&Bs[wn + j * 16 + l15][pg];
#pragma unroll
            for (int i = 0; i < AI; ++i)
#pragma unroll
                for (int j = 0; j < BJ; ++j)
                    acc[i][j] = __builtin_amdgcn_mfma_f32_16x16x32_bf16(
                        af[i], bw[j], acc[i][j], 0, 0, 0);
        }
        __syncthreads();
    }

    // epilogue. C/D layout: col = lane&15, row = quad*4 + reg  [m89-verified]
    unsigned short* op = out + ((SK > 1) ? (long)zslice * slice_stride : 0);
#pragma unroll
    for (int j = 0; j < BJ; ++j) {
        long col = n0 + wn + j * 16 + l15;
        float bv = (SK == 1 || zslice == 0) ? bias[col] : 0.f;
#pragma unroll
        for (int i = 0; i < AI; ++i) {
#pragma unroll
            for (int r = 0; r < 4; ++r) {
                long row = m0 + wm + i * 16 + qd * 4 + r;
                float v = acc[i][j][r] + bv;
                if (EPI == 1) v = (v > 0.f) ? v : 0.f;
                op[row * Ncols + col] = f2bf(v);
            }
        }
    }
}

template<int TM, int TN, int EPI, int SK>
__global__ __launch_bounds__(256) void gemm_bt(
    const unsigned short* __restrict__ A, const unsigned short* __restrict__ W,
    const float* __restrict__ bias, unsigned short* __restrict__ out,
    int K, int Ncols, long slice_stride)
{
    __shared__ unsigned short As[TM][64];
    __shared__ unsigned short Bs[TN][64];
    const int bid = blockIdx.y * gridDim.x + blockIdx.x;
    gemm_body<TM, TN, EPI, SK>(As, Bs, A, W, bias, out, K, Ncols, slice_stride,
                               bid, gridDim.x, (int)blockIdx.z);
}

// Two independent GEMMs (same tile shape) in one dispatch (crossQ + crossKV).
template<int TM, int TN>
__global__ __launch_bounds__(256) void gemm_bt_dual(
    const unsigned short* A0, const unsigned short* W0, const float* b0,
    unsigned short* o0, int K0, int N0, int gx0, int nb0,
    const unsigned short* A1, const unsigned short* W1, const float* b1,
    unsigned short* o1, int K1, int N1, int gx1)
{
    __shared__ unsigned short As[TM][64];
    __shared__ unsigned short Bs[TN][64];
    const int bid = blockIdx.x;
    if (bid < nb0)
        gemm_body<TM, TN, 0, 1>(As, Bs, A0, W0, b0, o0, K0, N0, 0, bid, gx0, 0);
    else
        gemm_body<TM, TN, 0, 1>(As, Bs, A1, W1, b1, o1, K1, N1, 0, bid - nb0, gx1, 0);
}

// --------------------------- flash attention (MFMA, 4-wave, 64q) -----------
// 64 queries/block, 1 q-tile/wave, 4 blocks/CU, fixed-reference softmax
// (M=0 exact: shift-invariance + O(1) scores), permuted key order
// key' = (k&15)*4 + (k>>4) in P and V, 2-stage K/V prefetch.
__global__ __launch_bounds__(256) void attn_kernel(
    const unsigned short* __restrict__ Qb, int q_stride,
    const unsigned short* __restrict__ KVb, int kv_stride, int koff, int voff,
    unsigned short* __restrict__ O,
    int Nq, int Mk, int causal)
{
    __shared__ unsigned short Ks[64][72];
    __shared__ unsigned short Vs[64][72];
    __shared__ unsigned short Ps[4][16][72];

    const int tid  = threadIdx.x;
    const int lane = tid & 63;
    const int wave = tid >> 6;
    const int qd   = lane >> 4;
    const int l15  = lane & 15;
    const int h    = blockIdx.y;
    const int b    = blockIdx.z;
    int jq = blockIdx.x;
    if (causal && (b & 1)) jq = gridDim.x - 1 - jq;
    const int q0 = jq * 64;
    const int tb = q0 + wave * 16;

    bf16x8 aq0, aq1;
    {
        const unsigned short* qp =
            Qb + (long)(b * Nq + tb + l15) * q_stride + h * 64 + qd * 8;
        aq0 = *(const bf16x8*)qp;
        aq1 = *(const bf16x8*)(qp + 32);
    }

    float lpart[4] = {};
    f32x4 oacc[4] = {};

    const int krow = tid >> 3;
    const int kcol = (tid & 7) * 8;
    const int vj   = tid & 31;
    const int va_k = (vj & 15) + ((vj & 16) << 1);
    const int vfg  = (tid >> 5) * 8;
    const int vpc  = (va_k & 15) * 4 + (va_k >> 4);

    const unsigned short* Kg = KVb + (long)b * Mk * kv_stride + koff + h * 64;
    const unsigned short* Vg = KVb + (long)b * Mk * kv_stride + voff + h * 64;

    bf16x8 kr0, kr1, vra, vrb;
    auto prefetch = [&](int k0) {
        kr0 = *(const bf16x8*)(Kg + (long)(k0 + krow) * kv_stride + kcol);
        kr1 = *(const bf16x8*)(Kg + (long)(k0 + krow + 32) * kv_stride + kcol);
        const unsigned short* v0 = Vg + (long)(k0 + va_k) * kv_stride + vfg;
        vra = *(const bf16x8*)v0;
        vrb = *(const bf16x8*)(v0 + 16 * kv_stride);
    };

    const int nk = causal ? (q0 + 64) : Mk;
    prefetch(0);
    const float SCL = 0.125f * 1.44269504f;

    for (int k0 = 0; k0 < nk; k0 += 64) {
        __syncthreads();
        *(bf16x8*)&Ks[krow][kcol]      = kr0;
        *(bf16x8*)&Ks[krow + 32][kcol] = kr1;
#pragma unroll
        for (int jf = 0; jf < 8; ++jf) {
            unsigned int d = (unsigned short)vra[jf] |
                             ((unsigned int)(unsigned short)vrb[jf] << 16);
            *(unsigned int*)&Vs[vfg + jf][vpc] = d;
        }
        if (k0 + 64 < nk) prefetch(k0 + 64);
        __syncthreads();

        if (!causal || (k0 <= tb + 15)) {
            bf16x8 bk[4][2];
#pragma unroll
            for (int kt = 0; kt < 4; ++kt)
#pragma unroll
                for (int c = 0; c < 2; ++c)
                    bk[kt][c] = *(const bf16x8*)&Ks[kt * 16 + l15][c * 32 + qd * 8];
            f32x4 s[4];
#pragma unroll
            for (int kt = 0; kt < 4; ++kt) {
                f32x4 z = {};
                z = __builtin_amdgcn_mfma_f32_16x16x32_bf16(aq0, bk[kt][0], z, 0, 0, 0);
                z = __builtin_amdgcn_mfma_f32_16x16x32_bf16(aq1, bk[kt][1], z, 0, 0, 0);
                s[kt] = z;
            }
            const bool needmask = causal && (k0 + 63 > tb);
#pragma unroll
            for (int r = 0; r < 4; ++r) {
                const int qg = tb + qd * 4 + r;
                float e[4];
#pragma unroll
                for (int kt = 0; kt < 4; ++kt) {
                    float ev = __builtin_amdgcn_exp2f(s[kt][r] * SCL);
                    if (needmask && (k0 + kt * 16 + l15 > qg)) ev = 0.f;
                    e[kt] = ev;
                }
                lpart[r] += (e[0] + e[1]) + (e[2] + e[3]);
                unsigned int lo = bftrunc(e[0]) | (bftrunc(e[1]) << 16);
                unsigned int hi = bftrunc(e[2]) | (bftrunc(e[3]) << 16);
                uint2 pk; pk.x = lo; pk.y = hi;
                *(uint2*)&Ps[wave][qd * 4 + r][l15 * 4] = pk;
            }
            bf16x8 bv[4][2];
#pragma unroll
            for (int dt = 0; dt < 4; ++dt)
#pragma unroll
                for (int c = 0; c < 2; ++c)
                    bv[dt][c] = *(const bf16x8*)&Vs[dt * 16 + l15][c * 32 + qd * 8];
            bf16x8 ap0 = *(const bf16x8*)&Ps[wave][l15][qd * 8];
            bf16x8 ap1 = *(const bf16x8*)&Ps[wave][l15][32 + qd * 8];
#pragma unroll
            for (int dt = 0; dt < 4; ++dt) {
                oacc[dt] = __builtin_amdgcn_mfma_f32_16x16x32_bf16(
                    ap0, bv[dt][0], oacc[dt], 0, 0, 0);
                oacc[dt] = __builtin_amdgcn_mfma_f32_16x16x32_bf16(
                    ap1, bv[dt][1], oacc[dt], 0, 0, 0);
            }
        }
    }

#pragma unroll
    for (int r = 0; r < 4; ++r) {
        float l = lpart[r];
        l += __shfl_xor(l, 1);
        l += __shfl_xor(l, 2);
        l += __shfl_xor(l, 4);
        l += __shfl_xor(l, 8);
        float inv = 1.f / l;
        long row = (long)(b * Nq + tb + qd * 4 + r);
#pragma unroll
        for (int dt = 0; dt < 4; ++dt)
            O[row * 1024 + h * 64 + dt * 16 + l15] = f2bf(oacc[dt][r] * inv);
    }
}

// --------------------------- residual + LayerNorm --------------------------
// res: fp32 (RESBF=0) or bf16 (RESBF=1). ND bf16 delta slices.
template<int ND, int RESBF>
__global__ __launch_bounds__(256) void ln_res_kernel(
    const void* __restrict__ res, const unsigned short* __restrict__ delta,
    long dstride, const float* __restrict__ g, const float* __restrict__ beta,
    float* __restrict__ yout, unsigned short* __restrict__ ybf)
{
    __shared__ float red[8];
    const int row = blockIdx.x;
    const int tid = threadIdx.x;
    const long base = (long)row * 1024 + tid * 4;
    float v0, v1, v2, v3;
    if (RESBF) {
        ushort4 a = *(const ushort4*)((const unsigned short*)res + base);
        v0 = bf2f(a.x); v1 = bf2f(a.y); v2 = bf2f(a.z); v3 = bf2f(a.w);
    } else {
        float4 a = *(const float4*)((const float*)res + base);
        v0 = a.x; v1 = a.y; v2 = a.z; v3 = a.w;
    }
#pragma unroll
    for (int t = 0; t < ND; ++t) {
        ushort4 d = *(const ushort4*)(delta + t * dstride + base);
        v0 += bf2f(d.x); v1 += bf2f(d.y); v2 += bf2f(d.z); v3 += bf2f(d.w);
    }
    float s  = v0 + v1 + v2 + v3;
    float ss = v0 * v0 + v1 * v1 + v2 * v2 + v3 * v3;
#pragma unroll
    for (int off = 1; off < 64; off <<= 1) {
        s  += __shfl_xor(s, off);
        ss += __shfl_xor(ss, off);
    }
    const int wave = tid >> 6;
    if ((tid & 63) == 0) { red[wave] = s; red[4 + wave] = ss; }
    __syncthreads();
    float st  = red[0] + red[1] + red[2] + red[3];
    float sst = red[4] + red[5] + red[6] + red[7];
    float mean = st * (1.f / 1024.f);
    float var  = sst * (1.f / 1024.f) - mean * mean;
    float inv  = rsqrtf(var + 1e-5f);
    const int c = tid * 4;
    float y0 = (v0 - mean) * inv * g[c + 0] + beta[c + 0];
    float y1 = (v1 - mean) * inv * g[c + 1] + beta[c + 1];
    float y2 = (v2 - mean) * inv * g[c + 2] + beta[c + 2];
    float y3 = (v3 - mean) * inv * g[c + 3] + beta[c + 3];
    if (yout) *(float4*)(yout + base) = make_float4(y0, y1, y2, y3);
    if (ybf) {
        ushort4 o;
        o.x = f2bf(y0); o.y = f2bf(y1); o.z = f2bf(y2); o.w = f2bf(y3);
        *(ushort4*)(ybf + base) = o;
    }
}

// --------------------------- launch ----------------------------------------
extern "C" void kernel_launch(void* const* d_in, const int* in_sizes, int n_in,
                              void* d_out, int out_size, void* d_ws, size_t ws_size,
                              hipStream_t stream)
{
    const int B = 2, N = 2048, M = 1024, D = 1024, FF = 4096;
    const int TN = B * N;   // 4096
    const int TM = B * M;   // 2048
    const size_t MB = 1024 * 1024;

    const float* x     = (const float*)d_in[0];
    const float* mem   = (const float*)d_in[1];
    const float* sa_wq = (const float*)d_in[3];  const float* sa_bq = (const float*)d_in[4];
    const float* sa_wk = (const float*)d_in[5];  const float* sa_bk = (const float*)d_in[6];
    const float* sa_wv = (const float*)d_in[7];  const float* sa_bv = (const float*)d_in[8];
    const float* sa_wo = (const float*)d_in[9];  const float* sa_bo = (const float*)d_in[10];
    const float* ca_wq = (const float*)d_in[11]; const float* ca_bq = (const float*)d_in[12];
    const float* ca_wk = (const float*)d_in[13]; const float* ca_bk = (const float*)d_in[14];
    const float* ca_wv = (const float*)d_in[15]; const float* ca_bv = (const float*)d_in[16];
    const float* ca_wo = (const float*)d_in[17]; const float* ca_bo = (const float*)d_in[18];
    const float* ff_w1 = (const float*)d_in[19]; const float* ff_b1 = (const float*)d_in[20];
    const float* ff_w2 = (const float*)d_in[21]; const float* ff_b2 = (const float*)d_in[22];
    const float* ln1_g = (const float*)d_in[23]; const float* ln1_b = (const float*)d_in[24];
    const float* ln2_g = (const float*)d_in[25]; const float* ln2_b = (const float*)d_in[26];
    const float* ln3_g = (const float*)d_in[27]; const float* ln3_b = (const float*)d_in[28];

    char* w = (char*)d_ws;
    size_t off = 0;
    auto alloc = [&](size_t bytes) -> char* {
        char* p = w + off; off += (bytes + 255) & ~(size_t)255; return p;
    };

    unsigned short* xb   = (unsigned short*)alloc((size_t)TN * D * 2);   // 8 MB
    unsigned short* memb = (unsigned short*)alloc((size_t)TM * D * 2);   // 4 MB
    unsigned short* wqkv = (unsigned short*)alloc((size_t)3 * D * D * 2);// 6 MB
    unsigned short* wos  = (unsigned short*)alloc((size_t)D * D * 2);
    unsigned short* wqc  = (unsigned short*)alloc((size_t)D * D * 2);
    unsigned short* wkvc = (unsigned short*)alloc((size_t)2 * D * D * 2);// 4 MB
    unsigned short* woc  = (unsigned short*)alloc((size_t)D * D * 2);
    unsigned short* w1b  = (unsigned short*)alloc((size_t)FF * D * 2);   // 8 MB
    unsigned short* w2b  = (unsigned short*)alloc((size_t)D * FF * 2);   // 8 MB
    // big overlapped region (64 MB), phase-disjoint liveness (as R9):
    //   phase1: qkv [0,24)  ab [24,32)  tmpbf [32,48)
    //   phase2: kvb [0,8)   qb [8,16)   ab [24,32)  tmpbf [32,48)
    //   phase3: hb  [0,32)  tmpbf [32,64) (4 slices)
    char* big = alloc((size_t)64 * MB);
    unsigned short* qkv   = (unsigned short*)big;
    unsigned short* kvb   = (unsigned short*)big;
    unsigned short* qb    = (unsigned short*)(big + 8 * MB);
    unsigned short* ab    = (unsigned short*)(big + 24 * MB);
    unsigned short* hb    = (unsigned short*)big;
    unsigned short* tmpbf = (unsigned short*)(big + 32 * MB);
    const long      TSL   = (long)TN * D;        // slice stride (elements)
    float* bqkv = (float*)alloc((size_t)3 * D * 4);
    float* bkvc = (float*)alloc((size_t)2 * D * 4);

    // ---- fused fp32->bf16 conversions + bias concat (one launch) ----
    ConvArgs ca;
    const float* srcs[12] = {x, mem, sa_wq, sa_wk, sa_wv, sa_wo,
                             ca_wq, ca_wk, ca_wv, ca_wo, ff_w1, ff_w2};
    unsigned short* dsts[12] = {xb, memb, wqkv, wqkv + (size_t)D * D,
                                wqkv + (size_t)2 * D * D, wos, wqc, wkvc,
                                wkvc + (size_t)D * D, woc, w1b, w2b};
    long ns[12] = {(long)TN * D, (long)TM * D, (long)D * D, (long)D * D,
                   (long)D * D, (long)D * D, (long)D * D, (long)D * D,
                   (long)D * D, (long)D * D, (long)FF * D, (long)D * FF};
    int total_blk = 0;
    for (int i = 0; i < 12; ++i) {
        ca.src[i] = srcs[i]; ca.dst[i] = dsts[i];
        ca.n4[i] = (int)(ns[i] / 4);
        ca.blk_ofs[i] = total_blk;
        total_blk += (ca.n4[i] + 255) / 256;
    }
    ca.blk_ofs[12] = total_blk;
    ca.bq = sa_bq; ca.bk = sa_bk; ca.bv = sa_bv; ca.ck = ca_bk; ca.cv = ca_bv;
    ca.bqkv = bqkv; ca.bkvc = bkvc;
    conv_multi<<<dim3(total_blk + 20), dim3(256), 0, stream>>>(ca);

    dim3 blk(256);

    // ---- self-attention ----
    gemm_bt<128, 64, 0, 1><<<dim3(3 * D / 64, TN / 128), blk, 0, stream>>>(
        xb, wqkv, bqkv, qkv, D, 3 * D, 0);
    attn_kernel<<<dim3(N / 64, 16, B), blk, 0, stream>>>(
        qkv, 3 * D, qkv, 3 * D, D, 2 * D, ab, N, N, 1);
    gemm_bt<128, 64, 0, 2><<<dim3(D / 64, TN / 128, 2), blk, 0, stream>>>(
        ab, wos, sa_bo, tmpbf, D, D, TSL);
    ln_res_kernel<2, 0><<<dim3(TN), blk, 0, stream>>>(
        x, tmpbf, TSL, ln1_g, ln1_b, nullptr, xb);

    // ---- cross-attention (Q + KV projections merged: 512+512 blocks) ----
    gemm_bt_dual<128, 64><<<dim3(1024), blk, 0, stream>>>(
        xb,   wqc,  ca_bq, qb,  D, D,     D / 64,  512,
        memb, wkvc, bkvc,  kvb, D, 2 * D, 2 * D / 64);
    attn_kernel<<<dim3(N / 64, 16, B), blk, 0, stream>>>(
        qb, D, kvb, 2 * D, 0, D, ab, N, M, 0);
    gemm_bt<128, 64, 0, 2><<<dim3(D / 64, TN / 128, 2), blk, 0, stream>>>(
        ab, woc, ca_bo, tmpbf, D, D, TSL);
    ln_res_kernel<2, 1><<<dim3(TN), blk, 0, stream>>>(
        xb, tmpbf, TSL, ln2_g, ln2_b, nullptr, xb);

    // ---- FFN ----
    gemm_bt<128, 128, 1, 1><<<dim3(FF / 128, TN / 128), blk, 0, stream>>>(
        xb, w1b, ff_b1, hb, D, FF, 0);
    gemm_bt<128, 64, 0, 4><<<dim3(D / 64, TN / 128, 4), blk, 0, stream>>>(
        hb, w2b, ff_b2, tmpbf, FF, D, TSL);
    ln_res_kernel<4, 1><<<dim3(TN), blk, 0, stream>>>(
        xb, tmpbf, TSL, ln3_g, ln3_b, (float*)d_out, nullptr);
}

// Round 12
// 478.294 us; speedup vs baseline: 1.0472x; 1.0189x over previous
//
#include <hip/hip_runtime.h>

// ---------------------------------------------------------------------------
// DecoderBlock: x = LN1(x + SelfAttn(x));  x = LN2(x + CrossAttn(x, mem));
//               x = LN3(x + W2·relu(W1·x + b1) + b2)
// B=2, N=2048, M=1024, D=1024, H=16, Dh=64, FF=4096.
// R12 = R11 (487us best) + two occupancy levers:
//   (1) FFN1 128x128 -> 128x64 (2048 blocks, ~6 blocks/CU vs 4; FFN1 was the
//       top dispatch at 51.5us / 668 TF / 63% combined pipe-busy).
//   (2) crossKV moved to phase 1, merged with selfQKV in one 128x64 dual
//       (2048 blocks = 8/CU); phase 2 keeps only crossQ.
// ---------------------------------------------------------------------------

typedef __attribute__((ext_vector_type(8))) short bf16x8;   // 8 bf16 (4 VGPRs)
typedef __attribute__((ext_vector_type(4))) float f32x4;

__device__ __forceinline__ unsigned short f2bf(float f) {
    union { float f; unsigned int u; } v; v.f = f;
    unsigned int r = v.u + 0x7fffu + ((v.u >> 16) & 1u);   // RNE
    return (unsigned short)(r >> 16);
}
__device__ __forceinline__ float bf2f(unsigned short u) {
    union { unsigned int u; float f; } v; v.u = (unsigned int)u << 16;
    return v.f;
}
__device__ __forceinline__ unsigned int bftrunc(float f) {
    union { float f; unsigned int u; } v; v.f = f;
    return v.u >> 16;                                      // truncation (P only)
}

// ------------------- fused fp32->bf16 conversion + bias concat -------------
struct ConvArgs {
    const float* src[12];
    unsigned short* dst[12];
    int blk_ofs[13];
    int n4[12];
    const float* bq; const float* bk; const float* bv;
    const float* ck; const float* cv;
    float* bqkv; float* bkvc;
};
__global__ __launch_bounds__(256) void conv_multi(ConvArgs a)
{
    int bid = blockIdx.x;
    if (bid >= a.blk_ofs[12]) {                  // bias-concat tail
        int i = (bid - a.blk_ofs[12]) * 256 + threadIdx.x;   // 0..5119
        if (i < 1024)       a.bqkv[i] = a.bq[i];
        else if (i < 2048)  a.bqkv[i] = a.bk[i - 1024];
        else if (i < 3072)  a.bqkv[i] = a.bv[i - 2048];
        else if (i < 4096)  a.bkvc[i - 3072] = a.ck[i - 3072];
        else if (i < 5120)  a.bkvc[i - 3072] = a.cv[i - 4096];
        return;
    }
    int s = 0;
#pragma unroll
    for (int t = 0; t < 12; ++t) if (bid >= a.blk_ofs[t + 1]) s = t + 1;
    int i = (bid - a.blk_ofs[s]) * 256 + threadIdx.x;
    if (i >= a.n4[s]) return;
    float4 v = ((const float4*)a.src[s])[i];
    ushort4 o;
    o.x = f2bf(v.x); o.y = f2bf(v.y); o.z = f2bf(v.z); o.w = f2bf(v.w);
    ((ushort4*)a.dst[s])[i] = o;
}

// --------------------------- bf16 GEMM core --------------------------------
// TM x TN tile, BK=64, 256 threads, global_load_lds width-16 staging,
// XOR-swizzled LDS (conflict-free; verified R8: SQ_LDS_BANK_CONFLICT = 0).
// All outputs bf16. EPI: 0 = plain, 1 = relu. SK>1: bf16 partial slices.
template<int TM, int TN, int EPI, int SK>
__device__ __forceinline__ void gemm_body(
    unsigned short (*As)[64], unsigned short (*Bs)[64],
    const unsigned short* __restrict__ A, const unsigned short* __restrict__ W,
    const float* __restrict__ bias, unsigned short* __restrict__ out,
    int K, int Ncols, long slice_stride, int bid, int gx, int zslice)
{
    constexpr int AI = TM / 32;
    constexpr int BJ = TN / 32;

    const int tid  = threadIdx.x;
    const int lane = tid & 63;
    const int wave = tid >> 6;
    const int qd   = lane >> 4;
    const int l15  = lane & 15;
    const int wm   = (wave >> 1) * (TM / 2);
    const int wn   = (wave & 1) * (TN / 2);

    const int gpg = 8 * gx;                       // GROUP_M=8 swizzle
    const long m0 = (long)((bid / gpg) * 8 + (bid & 7)) * TM;
    const long n0 = (long)((bid % gpg) >> 3) * TN;

    f32x4 acc[AI][BJ] = {};

    const int srow = lane >> 3;
    const int scol = (((lane & 7) ^ srow)) * 8;   // XOR-swizzled group
    const unsigned short* Ag = A + (m0 + wave * (8 * AI) + srow) * (long)K + scol;
    const unsigned short* Wg = W + (n0 + wave * (8 * BJ) + srow) * (long)K + scol;

    const int ksl   = K / SK;
    const int kbase = (SK > 1) ? zslice * ksl : 0;

    for (int k0 = kbase; k0 < kbase + ksl; k0 += 64) {
#pragma unroll
        for (int c = 0; c < AI; ++c)
            __builtin_amdgcn_global_load_lds(
                (const __attribute__((address_space(1))) unsigned int*)(Ag + (long)c * 8 * K + k0),
                (__attribute__((address_space(3))) unsigned int*)((char*)&As[0][0] + (wave * AI + c) * 1024),
                16, 0, 0);
#pragma unroll
        for (int c = 0; c < BJ; ++c)
            __builtin_amdgcn_global_load_lds(
                (const __attribute__((address_space(1))) unsigned int*)(Wg + (long)c * 8 * K + k0),
                (__attribute__((address_space(3))) unsigned int*)((char*)&Bs[0][0] + (wave * BJ + c) * 1024),
                16, 0, 0);
        __syncthreads();
#pragma unroll
        for (int kk = 0; kk < 64; kk += 32) {
            const int pg = ((((kk >> 3) + qd)) ^ (l15 & 7)) * 8;  // de-swizzle
            bf16x8 af[AI], bw[BJ];
#pragma unroll
            for (int i = 0; i < AI; ++i)
                af[i] = *(const bf16x8*)&As[wm + i * 16 + l15][pg];
#pragma unroll
            for (int j = 0; j < BJ; ++j)
                bw[j] = *(const bf16x8*)&Bs[wn + j * 16 + l15][pg];
#pragma unroll
            for (int i = 0; i < AI; ++i)
#pragma unroll
                for (int j = 0; j < BJ; ++j)
                    acc[i][j] = __builtin_amdgcn_mfma_f32_16x16x32_bf16(
                        af[i], bw[j], acc[i][j], 0, 0, 0);
        }
        __syncthreads();
    }

    // epilogue. C/D layout: col = lane&15, row = quad*4 + reg  [m89-verified]
    unsigned short* op = out + ((SK > 1) ? (long)zslice * slice_stride : 0);
#pragma unroll
    for (int j = 0; j < BJ; ++j) {
        long col = n0 + wn + j * 16 + l15;
        float bv = (SK == 1 || zslice == 0) ? bias[col] : 0.f;
#pragma unroll
        for (int i = 0; i < AI; ++i) {
#pragma unroll
            for (int r = 0; r < 4; ++r) {
                long row = m0 + wm + i * 16 + qd * 4 + r;
                float v = acc[i][j][r] + bv;
                if (EPI == 1) v = (v > 0.f) ? v : 0.f;
                op[row * Ncols + col] = f2bf(v);
            }
        }
    }
}

template<int TM, int TN, int EPI, int SK>
__global__ __launch_bounds__(256) void gemm_bt(
    const unsigned short* __restrict__ A, const unsigned short* __restrict__ W,
    const float* __restrict__ bias, unsigned short* __restrict__ out,
    int K, int Ncols, long slice_stride)
{
    __shared__ unsigned short As[TM][64];
    __shared__ unsigned short Bs[TN][64];
    const int bid = blockIdx.y * gridDim.x + blockIdx.x;
    gemm_body<TM, TN, EPI, SK>(As, Bs, A, W, bias, out, K, Ncols, slice_stride,
                               bid, gridDim.x, (int)blockIdx.z);
}

// Two independent GEMMs (same tile shape) in one dispatch (selfQKV + crossKV).
template<int TM, int TN>
__global__ __launch_bounds__(256) void gemm_bt_dual(
    const unsigned short* A0, const unsigned short* W0, const float* b0,
    unsigned short* o0, int K0, int N0, int gx0, int nb0,
    const unsigned short* A1, const unsigned short* W1, const float* b1,
    unsigned short* o1, int K1, int N1, int gx1)
{
    __shared__ unsigned short As[TM][64];
    __shared__ unsigned short Bs[TN][64];
    const int bid = blockIdx.x;
    if (bid < nb0)
        gemm_body<TM, TN, 0, 1>(As, Bs, A0, W0, b0, o0, K0, N0, 0, bid, gx0, 0);
    else
        gemm_body<TM, TN, 0, 1>(As, Bs, A1, W1, b1, o1, K1, N1, 0, bid - nb0, gx1, 0);
}

// --------------------------- flash attention (MFMA, 4-wave, 64q) -----------
// 64 queries/block, 1 q-tile/wave, 4 blocks/CU, fixed-reference softmax
// (M=0 exact: shift-invariance + O(1) scores), permuted key order
// key' = (k&15)*4 + (k>>4) in P and V, 2-stage K/V prefetch.
__global__ __launch_bounds__(256) void attn_kernel(
    const unsigned short* __restrict__ Qb, int q_stride,
    const unsigned short* __restrict__ KVb, int kv_stride, int koff, int voff,
    unsigned short* __restrict__ O,
    int Nq, int Mk, int causal)
{
    __shared__ unsigned short Ks[64][72];
    __shared__ unsigned short Vs[64][72];
    __shared__ unsigned short Ps[4][16][72];

    const int tid  = threadIdx.x;
    const int lane = tid & 63;
    const int wave = tid >> 6;
    const int qd   = lane >> 4;
    const int l15  = lane & 15;
    const int h    = blockIdx.y;
    const int b    = blockIdx.z;
    int jq = blockIdx.x;
    if (causal && (b & 1)) jq = gridDim.x - 1 - jq;
    const int q0 = jq * 64;
    const int tb = q0 + wave * 16;

    bf16x8 aq0, aq1;
    {
        const unsigned short* qp =
            Qb + (long)(b * Nq + tb + l15) * q_stride + h * 64 + qd * 8;
        aq0 = *(const bf16x8*)qp;
        aq1 = *(const bf16x8*)(qp + 32);
    }

    float lpart[4] = {};
    f32x4 oacc[4] = {};

    const int krow = tid >> 3;
    const int kcol = (tid & 7) * 8;
    const int vj   = tid & 31;
    const int va_k = (vj & 15) + ((vj & 16) << 1);
    const int vfg  = (tid >> 5) * 8;
    const int vpc  = (va_k & 15) * 4 + (va_k >> 4);

    const unsigned short* Kg = KVb + (long)b * Mk * kv_stride + koff + h * 64;
    const unsigned short* Vg = KVb + (long)b * Mk * kv_stride + voff + h * 64;

    bf16x8 kr0, kr1, vra, vrb;
    auto prefetch = [&](int k0) {
        kr0 = *(const bf16x8*)(Kg + (long)(k0 + krow) * kv_stride + kcol);
        kr1 = *(const bf16x8*)(Kg + (long)(k0 + krow + 32) * kv_stride + kcol);
        const unsigned short* v0 = Vg + (long)(k0 + va_k) * kv_stride + vfg;
        vra = *(const bf16x8*)v0;
        vrb = *(const bf16x8*)(v0 + 16 * kv_stride);
    };

    const int nk = causal ? (q0 + 64) : Mk;
    prefetch(0);
    const float SCL = 0.125f * 1.44269504f;

    for (int k0 = 0; k0 < nk; k0 += 64) {
        __syncthreads();
        *(bf16x8*)&Ks[krow][kcol]      = kr0;
        *(bf16x8*)&Ks[krow + 32][kcol] = kr1;
#pragma unroll
        for (int jf = 0; jf < 8; ++jf) {
            unsigned int d = (unsigned short)vra[jf] |
                             ((unsigned int)(unsigned short)vrb[jf] << 16);
            *(unsigned int*)&Vs[vfg + jf][vpc] = d;
        }
        if (k0 + 64 < nk) prefetch(k0 + 64);
        __syncthreads();

        if (!causal || (k0 <= tb + 15)) {
            bf16x8 bk[4][2];
#pragma unroll
            for (int kt = 0; kt < 4; ++kt)
#pragma unroll
                for (int c = 0; c < 2; ++c)
                    bk[kt][c] = *(const bf16x8*)&Ks[kt * 16 + l15][c * 32 + qd * 8];
            f32x4 s[4];
#pragma unroll
            for (int kt = 0; kt < 4; ++kt) {
                f32x4 z = {};
                z = __builtin_amdgcn_mfma_f32_16x16x32_bf16(aq0, bk[kt][0], z, 0, 0, 0);
                z = __builtin_amdgcn_mfma_f32_16x16x32_bf16(aq1, bk[kt][1], z, 0, 0, 0);
                s[kt] = z;
            }
            const bool needmask = causal && (k0 + 63 > tb);
#pragma unroll
            for (int r = 0; r < 4; ++r) {
                const int qg = tb + qd * 4 + r;
                float e[4];
#pragma unroll
                for (int kt = 0; kt < 4; ++kt) {
                    float ev = __builtin_amdgcn_exp2f(s[kt][r] * SCL);
                    if (needmask && (k0 + kt * 16 + l15 > qg)) ev = 0.f;
                    e[kt] = ev;
                }
                lpart[r] += (e[0] + e[1]) + (e[2] + e[3]);
                unsigned int lo = bftrunc(e[0]) | (bftrunc(e[1]) << 16);
                unsigned int hi = bftrunc(e[2]) | (bftrunc(e[3]) << 16);
                uint2 pk; pk.x = lo; pk.y = hi;
                *(uint2*)&Ps[wave][qd * 4 + r][l15 * 4] = pk;
            }
            bf16x8 bv[4][2];
#pragma unroll
            for (int dt = 0; dt < 4; ++dt)
#pragma unroll
                for (int c = 0; c < 2; ++c)
                    bv[dt][c] = *(const bf16x8*)&Vs[dt * 16 + l15][c * 32 + qd * 8];
            bf16x8 ap0 = *(const bf16x8*)&Ps[wave][l15][qd * 8];
            bf16x8 ap1 = *(const bf16x8*)&Ps[wave][l15][32 + qd * 8];
#pragma unroll
            for (int dt = 0; dt < 4; ++dt) {
                oacc[dt] = __builtin_amdgcn_mfma_f32_16x16x32_bf16(
                    ap0, bv[dt][0], oacc[dt], 0, 0, 0);
                oacc[dt] = __builtin_amdgcn_mfma_f32_16x16x32_bf16(
                    ap1, bv[dt][1], oacc[dt], 0, 0, 0);
            }
        }
    }

#pragma unroll
    for (int r = 0; r < 4; ++r) {
        float l = lpart[r];
        l += __shfl_xor(l, 1);
        l += __shfl_xor(l, 2);
        l += __shfl_xor(l, 4);
        l += __shfl_xor(l, 8);
        float inv = 1.f / l;
        long row = (long)(b * Nq + tb + qd * 4 + r);
#pragma unroll
        for (int dt = 0; dt < 4; ++dt)
            O[row * 1024 + h * 64 + dt * 16 + l15] = f2bf(oacc[dt][r] * inv);
    }
}

// --------------------------- residual + LayerNorm --------------------------
template<int ND, int RESBF>
__global__ __launch_bounds__(256) void ln_res_kernel(
    const void* __restrict__ res, const unsigned short* __restrict__ delta,
    long dstride, const float* __restrict__ g, const float* __restrict__ beta,
    float* __restrict__ yout, unsigned short* __restrict__ ybf)
{
    __shared__ float red[8];
    const int row = blockIdx.x;
    const int tid = threadIdx.x;
    const long base = (long)row * 1024 + tid * 4;
    float v0, v1, v2, v3;
    if (RESBF) {
        ushort4 a = *(const ushort4*)((const unsigned short*)res + base);
        v0 = bf2f(a.x); v1 = bf2f(a.y); v2 = bf2f(a.z); v3 = bf2f(a.w);
    } else {
        float4 a = *(const float4*)((const float*)res + base);
        v0 = a.x; v1 = a.y; v2 = a.z; v3 = a.w;
    }
#pragma unroll
    for (int t = 0; t < ND; ++t) {
        ushort4 d = *(const ushort4*)(delta + t * dstride + base);
        v0 += bf2f(d.x); v1 += bf2f(d.y); v2 += bf2f(d.z); v3 += bf2f(d.w);
    }
    float s  = v0 + v1 + v2 + v3;
    float ss = v0 * v0 + v1 * v1 + v2 * v2 + v3 * v3;
#pragma unroll
    for (int off = 1; off < 64; off <<= 1) {
        s  += __shfl_xor(s, off);
        ss += __shfl_xor(ss, off);
    }
    const int wave = tid >> 6;
    if ((tid & 63) == 0) { red[wave] = s; red[4 + wave] = ss; }
    __syncthreads();
    float st  = red[0] + red[1] + red[2] + red[3];
    float sst = red[4] + red[5] + red[6] + red[7];
    float mean = st * (1.f / 1024.f);
    float var  = sst * (1.f / 1024.f) - mean * mean;
    float inv  = rsqrtf(var + 1e-5f);
    const int c = tid * 4;
    float y0 = (v0 - mean) * inv * g[c + 0] + beta[c + 0];
    float y1 = (v1 - mean) * inv * g[c + 1] + beta[c + 1];
    float y2 = (v2 - mean) * inv * g[c + 2] + beta[c + 2];
    float y3 = (v3 - mean) * inv * g[c + 3] + beta[c + 3];
    if (yout) *(float4*)(yout + base) = make_float4(y0, y1, y2, y3);
    if (ybf) {
        ushort4 o;
        o.x = f2bf(y0); o.y = f2bf(y1); o.z = f2bf(y2); o.w = f2bf(y3);
        *(ushort4*)(ybf + base) = o;
    }
}

// --------------------------- launch ----------------------------------------
extern "C" void kernel_launch(void* const* d_in, const int* in_sizes, int n_in,
                              void* d_out, int out_size, void* d_ws, size_t ws_size,
                              hipStream_t stream)
{
    const int B = 2, N = 2048, M = 1024, D = 1024, FF = 4096;
    const int TN = B * N;   // 4096
    const int TM = B * M;   // 2048
    const size_t MB = 1024 * 1024;

    const float* x     = (const float*)d_in[0];
    const float* mem   = (const float*)d_in[1];
    const float* sa_wq = (const float*)d_in[3];  const float* sa_bq = (const float*)d_in[4];
    const float* sa_wk = (const float*)d_in[5];  const float* sa_bk = (const float*)d_in[6];
    const float* sa_wv = (const float*)d_in[7];  const float* sa_bv = (const float*)d_in[8];
    const float* sa_wo = (const float*)d_in[9];  const float* sa_bo = (const float*)d_in[10];
    const float* ca_wq = (const float*)d_in[11]; const float* ca_bq = (const float*)d_in[12];
    const float* ca_wk = (const float*)d_in[13]; const float* ca_bk = (const float*)d_in[14];
    const float* ca_wv = (const float*)d_in[15]; const float* ca_bv = (const float*)d_in[16];
    const float* ca_wo = (const float*)d_in[17]; const float* ca_bo = (const float*)d_in[18];
    const float* ff_w1 = (const float*)d_in[19]; const float* ff_b1 = (const float*)d_in[20];
    const float* ff_w2 = (const float*)d_in[21]; const float* ff_b2 = (const float*)d_in[22];
    const float* ln1_g = (const float*)d_in[23]; const float* ln1_b = (const float*)d_in[24];
    const float* ln2_g = (const float*)d_in[25]; const float* ln2_b = (const float*)d_in[26];
    const float* ln3_g = (const float*)d_in[27]; const float* ln3_b = (const float*)d_in[28];

    char* w = (char*)d_ws;
    size_t off = 0;
    auto alloc = [&](size_t bytes) -> char* {
        char* p = w + off; off += (bytes + 255) & ~(size_t)255; return p;
    };

    unsigned short* xb   = (unsigned short*)alloc((size_t)TN * D * 2);   // 8 MB
    unsigned short* memb = (unsigned short*)alloc((size_t)TM * D * 2);   // 4 MB
    unsigned short* wqkv = (unsigned short*)alloc((size_t)3 * D * D * 2);// 6 MB
    unsigned short* wos  = (unsigned short*)alloc((size_t)D * D * 2);
    unsigned short* wqc  = (unsigned short*)alloc((size_t)D * D * 2);
    unsigned short* wkvc = (unsigned short*)alloc((size_t)2 * D * D * 2);// 4 MB
    unsigned short* woc  = (unsigned short*)alloc((size_t)D * D * 2);
    unsigned short* w1b  = (unsigned short*)alloc((size_t)FF * D * 2);   // 8 MB
    unsigned short* w2b  = (unsigned short*)alloc((size_t)D * FF * 2);   // 8 MB
    // big overlapped region (80 MB), phase-disjoint liveness (R10 layout):
    //   phase1: qkv [0,24)  kvb [32,40)  ab [24,32)
    //   phase2: qb [40,48)  kvb [32,40)  ab [24,32)
    //   phase3: hb [0,32)
    //   partials: tmpbf [48,80) (up to 4 x 8 MB bf16 slices)
    char* big = alloc((size_t)80 * MB);
    unsigned short* qkv   = (unsigned short*)big;
    unsigned short* ab    = (unsigned short*)(big + 24 * MB);
    unsigned short* kvb   = (unsigned short*)(big + 32 * MB);
    unsigned short* qb    = (unsigned short*)(big + 40 * MB);
    unsigned short* hb    = (unsigned short*)big;
    unsigned short* tmpbf = (unsigned short*)(big + 48 * MB);
    const long      TSL   = (long)TN * D;        // slice stride (elements)
    float* bqkv = (float*)alloc((size_t)3 * D * 4);
    float* bkvc = (float*)alloc((size_t)2 * D * 4);

    // ---- fused fp32->bf16 conversions + bias concat (one launch) ----
    ConvArgs ca;
    const float* srcs[12] = {x, mem, sa_wq, sa_wk, sa_wv, sa_wo,
                             ca_wq, ca_wk, ca_wv, ca_wo, ff_w1, ff_w2};
    unsigned short* dsts[12] = {xb, memb, wqkv, wqkv + (size_t)D * D,
                                wqkv + (size_t)2 * D * D, wos, wqc, wkvc,
                                wkvc + (size_t)D * D, woc, w1b, w2b};
    long ns[12] = {(long)TN * D, (long)TM * D, (long)D * D, (long)D * D,
                   (long)D * D, (long)D * D, (long)D * D, (long)D * D,
                   (long)D * D, (long)D * D, (long)FF * D, (long)D * FF};
    int total_blk = 0;
    for (int i = 0; i < 12; ++i) {
        ca.src[i] = srcs[i]; ca.dst[i] = dsts[i];
        ca.n4[i] = (int)(ns[i] / 4);
        ca.blk_ofs[i] = total_blk;
        total_blk += (ca.n4[i] + 255) / 256;
    }
    ca.blk_ofs[12] = total_blk;
    ca.bq = sa_bq; ca.bk = sa_bk; ca.bv = sa_bv; ca.ck = ca_bk; ca.cv = ca_bv;
    ca.bqkv = bqkv; ca.bkvc = bkvc;
    conv_multi<<<dim3(total_blk + 20), dim3(256), 0, stream>>>(ca);

    dim3 blk(256);

    // ---- projections: self QKV (1536 blocks) + cross KV (512 blocks) ------
    gemm_bt_dual<128, 64><<<dim3(2048), blk, 0, stream>>>(
        xb,   wqkv, bqkv, qkv, D, 3 * D, 3 * D / 64, 1536,
        memb, wkvc, bkvc, kvb, D, 2 * D, 2 * D / 64);

    // ---- self-attention ----
    attn_kernel<<<dim3(N / 64, 16, B), blk, 0, stream>>>(
        qkv, 3 * D, qkv, 3 * D, D, 2 * D, ab, N, N, 1);
    gemm_bt<128, 64, 0, 2><<<dim3(D / 64, TN / 128, 2), blk, 0, stream>>>(
        ab, wos, sa_bo, tmpbf, D, D, TSL);
    ln_res_kernel<2, 0><<<dim3(TN), blk, 0, stream>>>(
        x, tmpbf, TSL, ln1_g, ln1_b, nullptr, xb);

    // ---- cross-attention ----
    gemm_bt<128, 64, 0, 1><<<dim3(D / 64, TN / 128), blk, 0, stream>>>(
        xb, wqc, ca_bq, qb, D, D, 0);
    attn_kernel<<<dim3(N / 64, 16, B), blk, 0, stream>>>(
        qb, D, kvb, 2 * D, 0, D, ab, N, M, 0);
    gemm_bt<128, 64, 0, 2><<<dim3(D / 64, TN / 128, 2), blk, 0, stream>>>(
        ab, woc, ca_bo, tmpbf, D, D, TSL);
    ln_res_kernel<2, 1><<<dim3(TN), blk, 0, stream>>>(
        xb, tmpbf, TSL, ln2_g, ln2_b, nullptr, xb);

    // ---- FFN ----
    gemm_bt<128, 64, 1, 1><<<dim3(FF / 64, TN / 128), blk, 0, stream>>>(
        xb, w1b, ff_b1, hb, D, FF, 0);
    gemm_bt<128, 64, 0, 4><<<dim3(D / 64, TN / 128, 4), blk, 0, stream>>>(
        hb, w2b, ff_b2, tmpbf, FF, D, TSL);
    ln_res_kernel<4, 1><<<dim3(TN), blk, 0, stream>>>(
        xb, tmpbf, TSL, ln3_g, ln3_b, (float*)d_out, nullptr);
}